// Round 4
// baseline (157.412 us; speedup 1.0000x reference)
//
#include <hip/hip_runtime.h>
#include <hip/hip_bf16.h>
#include <cstdint>
#include <cstddef>

#define N_NODES_C 10000
#define IN_FEATS 256
#define NUM_HEADS 8
#define OUT_FEATS 64
#define HD 512   // NUM_HEADS*OUT_FEATS
#define CH 32    // edges per chunk in agg

typedef __attribute__((ext_vector_type(8))) short bf16x8;
typedef __attribute__((ext_vector_type(4))) float f32x4;

__device__ inline unsigned short bf16_bits(float f) {
    unsigned x = __float_as_uint(f);
    x += 0x7fffu + ((x >> 16) & 1u);  // RNE
    return (unsigned short)(x >> 16);
}
__device__ inline unsigned pack_bf2(float a, float b) {
    return ((unsigned)bf16_bits(a)) | (((unsigned)bf16_bits(b)) << 16);
}

// ---------------- K1: count | Wt transpose | wlr  (block-range fused) ----------------

__global__ __launch_bounds__(256) void k1_kernel(const float* __restrict__ W,
                                                 const float* __restrict__ al,
                                                 const float* __restrict__ ar,
                                                 const int* __restrict__ dst,
                                                 int* __restrict__ deg,
                                                 float* __restrict__ wlr,
                                                 unsigned short* __restrict__ Wt,
                                                 int E, int nb_cnt) {
    const int b = blockIdx.x;
    const int t = threadIdx.x;
    if (b < nb_cnt) {
        // count: histogram of dst
        int i = b * 256 + t;
        if (i < E) atomicAdd(&deg[dst[i]], 1);
        return;
    }
    if (b < nb_cnt + 32) {
        // Wt[h][d][k] = bf16(W[k][h*64+d])
        __shared__ float tile[64][65];
        const int bb = b - nb_cnt;
        const int h = bb >> 2;
        const int k0 = (bb & 3) * 64;
#pragma unroll 4
        for (int it = 0; it < 16; ++it) {
            int r = it * 4 + (t >> 6);
            int c = t & 63;
            tile[r][c] = W[(size_t)(k0 + r) * HD + h * 64 + c];
        }
        __syncthreads();
#pragma unroll 4
        for (int it = 0; it < 16; ++it) {
            int c = it * 4 + (t >> 6);
            int k = t & 63;
            Wt[((size_t)h * 64 + c) * IN_FEATS + k0 + k] = bf16_bits(tile[k][c]);
        }
        return;
    }
    // wlr[k][0..7]=W_k . attn_l (per head), [8..15]=W_k . attn_r
    const int k = (b - nb_cnt - 32) * 4 + (t >> 6);
    const int l = t & 63;
    float4 w0 = *(const float4*)(W + (size_t)k * HD + 8 * l);
    float4 w1 = *(const float4*)(W + (size_t)k * HD + 8 * l + 4);
    float4 a0 = *(const float4*)(al + 8 * l);
    float4 a1 = *(const float4*)(al + 8 * l + 4);
    float4 b0 = *(const float4*)(ar + 8 * l);
    float4 b1 = *(const float4*)(ar + 8 * l + 4);
    float pl = w0.x * a0.x + w0.y * a0.y + w0.z * a0.z + w0.w * a0.w +
               w1.x * a1.x + w1.y * a1.y + w1.z * a1.z + w1.w * a1.w;
    float pr = w0.x * b0.x + w0.y * b0.y + w0.z * b0.z + w0.w * b0.w +
               w1.x * b1.x + w1.y * b1.y + w1.z * b1.z + w1.w * b1.w;
#pragma unroll
    for (int off = 1; off < 8; off <<= 1) {
        pl += __shfl_xor(pl, off);
        pr += __shfl_xor(pr, off);
    }
    if ((l & 7) == 0) {
        wlr[k * 16 + (l >> 3)] = pl;
        wlr[k * 16 + 8 + (l >> 3)] = pr;
    }
}

// ---------------- scan ----------------

__global__ __launch_bounds__(1024) void scan_kernel(const int* __restrict__ deg,
                                                    int* __restrict__ row_start,
                                                    int* __restrict__ cursor, int N) {
    __shared__ int wsum[16];
    __shared__ int woff[16];
    const int t = threadIdx.x;
    const int C = (N + 1023) / 1024;
    const int beg = t * C;
    const int end = min(beg + C, N);
    int s = 0;
    for (int i = beg; i < end; ++i) s += deg[i];
    const int lane = t & 63, wv = t >> 6;
    int v = s;
#pragma unroll
    for (int off = 1; off < 64; off <<= 1) {
        int u = __shfl_up(v, off);
        if (lane >= off) v += u;
    }
    if (lane == 63) wsum[wv] = v;
    __syncthreads();
    if (t == 0) {
        int run = 0;
#pragma unroll
        for (int i = 0; i < 16; ++i) { woff[i] = run; run += wsum[i]; }
        row_start[N] = run;
    }
    __syncthreads();
    int run = woff[wv] + v - s;  // exclusive prefix
    for (int i = beg; i < end; ++i) {
        row_start[i] = run;
        cursor[i] = run;
        run += deg[i];
    }
}

// ---------------- K3: scatter | elr  (block-range fused) ----------------

__global__ __launch_bounds__(256) void k3_kernel(const int* __restrict__ src,
                                                 const int* __restrict__ dst,
                                                 int* __restrict__ cursor,
                                                 int* __restrict__ slot_src,
                                                 const float* __restrict__ feat,
                                                 const float* __restrict__ wlr,
                                                 float* __restrict__ el,
                                                 float* __restrict__ er,
                                                 int E, int M, int nb_sc) {
    const int b = blockIdx.x;
    const int t = threadIdx.x;
    if (b < nb_sc) {
        int i = b * 256 + t;
        if (i < E) {
            int p = atomicAdd(&cursor[dst[i]], 1);
            slot_src[p] = src[i];
        }
        return;
    }
    // elr: el/er = feat @ wlr
    __shared__ float wle[256][17];
    for (int i = t; i < 256 * 16; i += 256) wle[i >> 4][i & 15] = wlr[i];
    __syncthreads();
    const int lane = t & 63, wv = t >> 6;
    const int n = (b - nb_sc) * 4 + wv;
    if (n >= M) return;
    const float* frow = feat + (size_t)n * IN_FEATS;
    float p[16];
#pragma unroll
    for (int h = 0; h < 16; ++h) p[h] = 0.f;
#pragma unroll
    for (int j = 0; j < 4; ++j) {
        int k = lane + 64 * j;
        float fv = frow[k];
#pragma unroll
        for (int h = 0; h < 16; ++h) p[h] = fmaf(fv, wle[k][h], p[h]);
    }
    float outv = 0.f;
#pragma unroll
    for (int h = 0; h < 16; ++h) {
        float v = p[h];
#pragma unroll
        for (int off = 32; off; off >>= 1) v += __shfl_xor(v, off);
        outv = (lane == h) ? v : outv;
    }
    if (lane < 8) el[n * NUM_HEADS + lane] = outv;
    else if (lane < 16) er[n * NUM_HEADS + lane - 8] = outv;
}

// ---------------- agg: hb[n,h,k] = (sum_j p_j*adj_j*feat[s_j,k]) / sum_j p_j ----------------
// thread t -> dim pair p = t>>1 (dims 2p,2p+1), head quad g = t&1 (heads 4g..4g+3)

__global__ __launch_bounds__(256) void agg_kernel(
    const float* __restrict__ feat, const float* __restrict__ el,
    const float* __restrict__ er, const float* __restrict__ adj,
    const int* __restrict__ row_start, const int* __restrict__ slot_src,
    const int* __restrict__ idxp, unsigned short* __restrict__ hb) {
    const int n = blockIdx.x;
    const int t = threadIdx.x;
    const int row = row_start[n];
    const int cnt = row_start[n + 1] - row;
    const int pp = t >> 1;   // dim pair
    const int g = t & 1;     // head quad
    if (cnt == 0) {
#pragma unroll
        for (int h = 0; h < 4; ++h)
            *(unsigned*)&hb[(size_t)n * 2048 + (4 * g + h) * 256 + 2 * pp] = 0u;
        return;
    }
    const int idx = idxp[0];
    const int hh = t & 7;
    const int j0 = t >> 3;  // 0..31
    const float er_hh = er[n * NUM_HEADS + hh];
    const float* adj_col = adj + (size_t)idx * N_NODES_C + (n + idx);

    __shared__ float w_lds[2][CH][8];
    __shared__ int s_lds[2][CH];
    __shared__ float red[256];
    __shared__ float inv_s[8];

    float ssum = 0.f;
    float acc[8] = {0.f, 0.f, 0.f, 0.f, 0.f, 0.f, 0.f, 0.f};  // [dim d][head h] = acc[d*4+h]
    int buf = 0;
    for (int base = 0; base < cnt; base += CH) {
        int j = base + j0;
        if (j < cnt) {
            int s = slot_src[row + j];
            float e = el[s * NUM_HEADS + hh] + er_hh;
            e = (e > 0.f) ? e : 0.2f * e;
            float pv = __expf(e);
            ssum += pv;
            w_lds[buf][j0][hh] = pv * adj_col[(size_t)s * N_NODES_C];
            if (hh == 0) s_lds[buf][j0] = s;
        }
        __syncthreads();
        int c = min(CH, cnt - base);
#pragma unroll 4
        for (int jj = 0; jj < c; ++jj) {
            int s = s_lds[buf][jj];
            float2 fv = *(const float2*)(feat + (size_t)s * IN_FEATS + 2 * pp);
            float4 w = *(const float4*)&w_lds[buf][jj][4 * g];
            acc[0] = fmaf(w.x, fv.x, acc[0]);
            acc[1] = fmaf(w.y, fv.x, acc[1]);
            acc[2] = fmaf(w.z, fv.x, acc[2]);
            acc[3] = fmaf(w.w, fv.x, acc[3]);
            acc[4] = fmaf(w.x, fv.y, acc[4]);
            acc[5] = fmaf(w.y, fv.y, acc[5]);
            acc[6] = fmaf(w.z, fv.y, acc[6]);
            acc[7] = fmaf(w.w, fv.y, acc[7]);
        }
        buf ^= 1;
    }
    red[t] = ssum;
    __syncthreads();
#pragma unroll
    for (int off = 128; off >= 8; off >>= 1) {
        if (t < off) red[t] += red[t + off];
        __syncthreads();
    }
    if (t < 8) inv_s[t] = 1.f / red[t];
    __syncthreads();
#pragma unroll
    for (int h = 0; h < 4; ++h) {
        float inv = inv_s[4 * g + h];
        unsigned pk = pack_bf2(acc[h] * inv, acc[4 + h] * inv);
        *(unsigned*)&hb[(size_t)n * 2048 + (4 * g + h) * 256 + 2 * pp] = pk;
    }
}

// ---------------- out[n, h*64+d] = sum_k hb[n,h,k] * Wt[h,d,k]  (bf16 MFMA) ----------------

__global__ __launch_bounds__(256) void out_gemm_kernel(const short* __restrict__ hb,
                                                       const short* __restrict__ Wt,
                                                       float* __restrict__ out, int M) {
    const int t = threadIdx.x;
    const int lane = t & 63, wv = t >> 6;
    const int by = blockIdx.y;               // head
    const int n0 = blockIdx.x * 64 + wv * 16;
    const int r = lane & 15;
    const int kg = lane >> 4;                // 0..3
    const int arow = min(n0 + r, M - 1);
    const short* aptr = hb + (size_t)arow * 2048 + by * IN_FEATS + kg * 8;
    const short* bptr = Wt + ((size_t)by * 64 + r) * IN_FEATS + kg * 8;
    f32x4 acc[4];
#pragma unroll
    for (int c = 0; c < 4; ++c) acc[c] = (f32x4){0.f, 0.f, 0.f, 0.f};
#pragma unroll
    for (int kk = 0; kk < IN_FEATS; kk += 32) {
        bf16x8 a = *(const bf16x8*)(aptr + kk);
#pragma unroll
        for (int c = 0; c < 4; ++c) {
            bf16x8 b = *(const bf16x8*)(bptr + (size_t)c * 16 * IN_FEATS + kk);
            acc[c] = __builtin_amdgcn_mfma_f32_16x16x32_bf16(a, b, acc[c], 0, 0, 0);
        }
    }
    const int orow0 = n0 + kg * 4;
#pragma unroll
    for (int c = 0; c < 4; ++c) {
#pragma unroll
        for (int i = 0; i < 4; ++i) {
            int rr = orow0 + i;
            if (rr < M) out[(size_t)rr * HD + by * 64 + c * 16 + r] = acc[c][i];
        }
    }
}

// ---------------- launch ----------------

extern "C" void kernel_launch(void* const* d_in, const int* in_sizes, int n_in,
                              void* d_out, int out_size, void* d_ws, size_t ws_size,
                              hipStream_t stream) {
    const float* feat   = (const float*)d_in[0];
    const float* W      = (const float*)d_in[1];
    const float* attn_l = (const float*)d_in[2];
    const float* attn_r = (const float*)d_in[3];
    const float* adj    = (const float*)d_in[4];
    const int*   src    = (const int*)d_in[5];
    const int*   dst    = (const int*)d_in[6];
    const int*   idxp   = (const int*)d_in[7];
    float* out = (float*)d_out;

    const int M = in_sizes[0] / IN_FEATS;  // 10000
    const int E = in_sizes[5];             // 320000

    char* ws = (char*)d_ws;
    size_t off = 0;
    auto alloc = [&](size_t bytes) -> void* {
        off = (off + 255) & ~(size_t)255;
        void* p = ws + off;
        off += bytes;
        return p;
    };
    unsigned short* hbuf  = (unsigned short*)alloc((size_t)M * 2048 * sizeof(short));
    unsigned short* Wt    = (unsigned short*)alloc((size_t)HD * IN_FEATS * sizeof(short));
    float* wlr       = (float*)alloc((size_t)IN_FEATS * 16 * sizeof(float));
    float* el        = (float*)alloc((size_t)M * NUM_HEADS * sizeof(float));
    float* er        = (float*)alloc((size_t)M * NUM_HEADS * sizeof(float));
    int*   deg       = (int*)alloc((size_t)M * sizeof(int));
    int*   row_start = (int*)alloc((size_t)(M + 1) * sizeof(int));
    int*   cursor    = (int*)alloc((size_t)M * sizeof(int));
    int*   slot_src  = (int*)alloc((size_t)E * sizeof(int));

    hipMemsetAsync(deg, 0, (size_t)M * sizeof(int), stream);

    const int nb_cnt = (E + 255) / 256;            // 1250
    const int nb_wlr = IN_FEATS / 4;               // 64
    k1_kernel<<<nb_cnt + 32 + nb_wlr, 256, 0, stream>>>(W, attn_l, attn_r, dst, deg,
                                                        wlr, Wt, E, nb_cnt);
    scan_kernel<<<1, 1024, 0, stream>>>(deg, row_start, cursor, M);
    const int nb_elr = (M + 3) / 4;                // 2500
    k3_kernel<<<nb_cnt + nb_elr, 256, 0, stream>>>(src, dst, cursor, slot_src,
                                                   feat, wlr, el, er, E, M, nb_cnt);
    agg_kernel<<<M, 256, 0, stream>>>(feat, el, er, adj, row_start, slot_src, idxp, hbuf);
    dim3 og((M + 63) / 64, NUM_HEADS);
    out_gemm_kernel<<<og, 256, 0, stream>>>((const short*)hbuf, (const short*)Wt, out, M);
}

// Round 5
// 147.446 us; speedup vs baseline: 1.0676x; 1.0676x over previous
//
#include <hip/hip_runtime.h>
#include <hip/hip_bf16.h>
#include <cstdint>
#include <cstddef>

#define N_NODES_C 10000
#define IN_FEATS 256
#define NUM_HEADS 8
#define OUT_FEATS 64
#define HD 512   // NUM_HEADS*OUT_FEATS
#define CH 32    // edges per chunk in agg

typedef __attribute__((ext_vector_type(8))) short bf16x8;
typedef __attribute__((ext_vector_type(4))) float f32x4;

__device__ inline unsigned short bf16_bits(float f) {
    unsigned x = __float_as_uint(f);
    x += 0x7fffu + ((x >> 16) & 1u);  // RNE
    return (unsigned short)(x >> 16);
}
__device__ inline unsigned pack_bf2(float a, float b) {
    return ((unsigned)bf16_bits(a)) | (((unsigned)bf16_bits(b)) << 16);
}

// ---------------- K1: count | Wt transpose | wlr  (block-range fused) ----------------

__global__ __launch_bounds__(256) void k1_kernel(const float* __restrict__ W,
                                                 const float* __restrict__ al,
                                                 const float* __restrict__ ar,
                                                 const int* __restrict__ dst,
                                                 int* __restrict__ deg,
                                                 float* __restrict__ wlr,
                                                 unsigned short* __restrict__ Wt,
                                                 int E, int nb_cnt) {
    const int b = blockIdx.x;
    const int t = threadIdx.x;
    if (b < nb_cnt) {
        // count: histogram of dst
        int i = b * 256 + t;
        if (i < E) atomicAdd(&deg[dst[i]], 1);
        return;
    }
    if (b < nb_cnt + 32) {
        // Wt[h][d][k] = bf16(W[k][h*64+d])
        __shared__ float tile[64][65];
        const int bb = b - nb_cnt;
        const int h = bb >> 2;
        const int k0 = (bb & 3) * 64;
#pragma unroll 4
        for (int it = 0; it < 16; ++it) {
            int r = it * 4 + (t >> 6);
            int c = t & 63;
            tile[r][c] = W[(size_t)(k0 + r) * HD + h * 64 + c];
        }
        __syncthreads();
#pragma unroll 4
        for (int it = 0; it < 16; ++it) {
            int c = it * 4 + (t >> 6);
            int k = t & 63;
            Wt[((size_t)h * 64 + c) * IN_FEATS + k0 + k] = bf16_bits(tile[k][c]);
        }
        return;
    }
    // wlr[k][0..7]=W_k . attn_l (per head), [8..15]=W_k . attn_r
    const int k = (b - nb_cnt - 32) * 4 + (t >> 6);
    const int l = t & 63;
    float4 w0 = *(const float4*)(W + (size_t)k * HD + 8 * l);
    float4 w1 = *(const float4*)(W + (size_t)k * HD + 8 * l + 4);
    float4 a0 = *(const float4*)(al + 8 * l);
    float4 a1 = *(const float4*)(al + 8 * l + 4);
    float4 b0 = *(const float4*)(ar + 8 * l);
    float4 b1 = *(const float4*)(ar + 8 * l + 4);
    float pl = w0.x * a0.x + w0.y * a0.y + w0.z * a0.z + w0.w * a0.w +
               w1.x * a1.x + w1.y * a1.y + w1.z * a1.z + w1.w * a1.w;
    float pr = w0.x * b0.x + w0.y * b0.y + w0.z * b0.z + w0.w * b0.w +
               w1.x * b1.x + w1.y * b1.y + w1.z * b1.z + w1.w * b1.w;
#pragma unroll
    for (int off = 1; off < 8; off <<= 1) {
        pl += __shfl_xor(pl, off);
        pr += __shfl_xor(pr, off);
    }
    if ((l & 7) == 0) {
        wlr[k * 16 + (l >> 3)] = pl;
        wlr[k * 16 + 8 + (l >> 3)] = pr;
    }
}

// ---------------- scan ----------------

__global__ __launch_bounds__(1024) void scan_kernel(const int* __restrict__ deg,
                                                    int* __restrict__ row_start,
                                                    int* __restrict__ cursor, int N) {
    __shared__ int wsum[16];
    __shared__ int woff[16];
    const int t = threadIdx.x;
    const int C = (N + 1023) / 1024;
    const int beg = t * C;
    const int end = min(beg + C, N);
    int s = 0;
    for (int i = beg; i < end; ++i) s += deg[i];
    const int lane = t & 63, wv = t >> 6;
    int v = s;
#pragma unroll
    for (int off = 1; off < 64; off <<= 1) {
        int u = __shfl_up(v, off);
        if (lane >= off) v += u;
    }
    if (lane == 63) wsum[wv] = v;
    __syncthreads();
    if (t == 0) {
        int run = 0;
#pragma unroll
        for (int i = 0; i < 16; ++i) { woff[i] = run; run += wsum[i]; }
        row_start[N] = run;
    }
    __syncthreads();
    int run = woff[wv] + v - s;  // exclusive prefix
    for (int i = beg; i < end; ++i) {
        row_start[i] = run;
        cursor[i] = run;
        run += deg[i];
    }
}

// ---------------- K3: scatter | elr (+ featb bf16 copy)  (block-range fused) ----------------

__global__ __launch_bounds__(256) void k3_kernel(const int* __restrict__ src,
                                                 const int* __restrict__ dst,
                                                 int* __restrict__ cursor,
                                                 int* __restrict__ slot_src,
                                                 const float* __restrict__ feat,
                                                 const float* __restrict__ wlr,
                                                 float* __restrict__ el,
                                                 float* __restrict__ er,
                                                 unsigned short* __restrict__ featb,
                                                 int E, int M, int nb_sc) {
    const int b = blockIdx.x;
    const int t = threadIdx.x;
    if (b < nb_sc) {
        int i = b * 256 + t;
        if (i < E) {
            int p = atomicAdd(&cursor[dst[i]], 1);
            slot_src[p] = src[i];
        }
        return;
    }
    // elr: el/er = feat @ wlr ; featb = bf16(feat)
    __shared__ float wle[256][17];
    for (int i = t; i < 256 * 16; i += 256) wle[i >> 4][i & 15] = wlr[i];
    __syncthreads();
    const int lane = t & 63, wv = t >> 6;
    const int n = (b - nb_sc) * 4 + wv;
    if (n >= M) return;
    const float* frow = feat + (size_t)n * IN_FEATS;
    unsigned short* fbrow = featb + (size_t)n * IN_FEATS;
    float p[16];
#pragma unroll
    for (int h = 0; h < 16; ++h) p[h] = 0.f;
#pragma unroll
    for (int j = 0; j < 4; ++j) {
        int k = lane + 64 * j;
        float fv = frow[k];
        fbrow[k] = bf16_bits(fv);
#pragma unroll
        for (int h = 0; h < 16; ++h) p[h] = fmaf(fv, wle[k][h], p[h]);
    }
    float outv = 0.f;
#pragma unroll
    for (int h = 0; h < 16; ++h) {
        float v = p[h];
#pragma unroll
        for (int off = 32; off; off >>= 1) v += __shfl_xor(v, off);
        outv = (lane == h) ? v : outv;
    }
    if (lane < 8) el[n * NUM_HEADS + lane] = outv;
    else if (lane < 16) er[n * NUM_HEADS + lane - 8] = outv;
}

// ---------------- agg: hb[n,h,k] = (sum_j p_j*adj_j*featb[s_j,k]) / sum_j p_j ----------------
// thread t -> dim pair pp = t>>1 (dims 2pp,2pp+1), head quad g = t&1 (heads 4g..4g+3)
// register-staged prefetch: next chunk's (slot_src, el, adj) loads issue before
// current chunk's inner loop, hiding HBM latency under compute.

__global__ __launch_bounds__(256) void agg_kernel(
    const unsigned short* __restrict__ featb, const float* __restrict__ el,
    const float* __restrict__ er, const float* __restrict__ adj,
    const int* __restrict__ row_start, const int* __restrict__ slot_src,
    const int* __restrict__ idxp, unsigned short* __restrict__ hb) {
    const int n = blockIdx.x;
    const int t = threadIdx.x;
    const int row = row_start[n];
    const int cnt = row_start[n + 1] - row;
    const int pp = t >> 1;   // dim pair
    const int g = t & 1;     // head quad
    if (cnt == 0) {
#pragma unroll
        for (int h = 0; h < 4; ++h)
            *(unsigned*)&hb[(size_t)n * 2048 + (4 * g + h) * 256 + 2 * pp] = 0u;
        return;
    }
    const int idx = idxp[0];
    const int hh = t & 7;
    const int j0 = t >> 3;  // 0..31
    const float er_hh = er[n * NUM_HEADS + hh];
    const float* adj_col = adj + (size_t)idx * N_NODES_C + (n + idx);

    __shared__ float w_lds[2][CH][8];
    __shared__ int s_lds[2][CH];
    __shared__ float red[256];
    __shared__ float inv_s[8];

    float ssum = 0.f;
    float acc[8] = {0.f, 0.f, 0.f, 0.f, 0.f, 0.f, 0.f, 0.f};  // [dim d][head h] = acc[d*4+h]

    int s_r = 0;
    float w_r = 0.f;
    auto stage = [&](int base) {
        int j = base + j0;
        if (j < cnt) {
            s_r = slot_src[row + j];
            float e = el[s_r * NUM_HEADS + hh] + er_hh;
            e = (e > 0.f) ? e : 0.2f * e;
            float pv = __expf(e);
            ssum += pv;
            w_r = pv * adj_col[(size_t)s_r * N_NODES_C];
        }
    };
    auto write_lds = [&](int buf, int base) {
        int j = base + j0;
        if (j < cnt) {
            w_lds[buf][j0][hh] = w_r;
            if (hh == 0) s_lds[buf][j0] = s_r;
        }
    };

    int buf = 0;
    stage(0);
    write_lds(0, 0);
    __syncthreads();
    for (int base = 0; base < cnt; base += CH) {
        const bool more = (base + CH) < cnt;
        if (more) stage(base + CH);
        int c = min(CH, cnt - base);
        const int* srow = &s_lds[buf][0];
        const float* wrow = &w_lds[buf][0][0];
#pragma unroll 4
        for (int jj = 0; jj < c; ++jj) {
            int s = srow[jj];
            unsigned u = *(const unsigned*)(featb + (size_t)s * IN_FEATS + 2 * pp);
            float fx = __uint_as_float((u & 0xffffu) << 16);
            float fy = __uint_as_float(u & 0xffff0000u);
            float4 w = *(const float4*)&wrow[jj * 8 + 4 * g];
            acc[0] = fmaf(w.x, fx, acc[0]);
            acc[1] = fmaf(w.y, fx, acc[1]);
            acc[2] = fmaf(w.z, fx, acc[2]);
            acc[3] = fmaf(w.w, fx, acc[3]);
            acc[4] = fmaf(w.x, fy, acc[4]);
            acc[5] = fmaf(w.y, fy, acc[5]);
            acc[6] = fmaf(w.z, fy, acc[6]);
            acc[7] = fmaf(w.w, fy, acc[7]);
        }
        if (more) {
            write_lds(buf ^ 1, base + CH);
            __syncthreads();
            buf ^= 1;
        }
    }
    red[t] = ssum;
    __syncthreads();
#pragma unroll
    for (int off = 128; off >= 8; off >>= 1) {
        if (t < off) red[t] += red[t + off];
        __syncthreads();
    }
    if (t < 8) inv_s[t] = 1.f / red[t];
    __syncthreads();
#pragma unroll
    for (int h = 0; h < 4; ++h) {
        float inv = inv_s[4 * g + h];
        unsigned pk = pack_bf2(acc[h] * inv, acc[4 + h] * inv);
        *(unsigned*)&hb[(size_t)n * 2048 + (4 * g + h) * 256 + 2 * pp] = pk;
    }
}

// ---------------- out[n, h*64+d] = sum_k hb[n,h,k] * Wt[h,d,k]  (bf16 MFMA) ----------------

__global__ __launch_bounds__(256) void out_gemm_kernel(const short* __restrict__ hb,
                                                       const short* __restrict__ Wt,
                                                       float* __restrict__ out, int M) {
    const int t = threadIdx.x;
    const int lane = t & 63, wv = t >> 6;
    const int by = blockIdx.y;               // head
    const int n0 = blockIdx.x * 64 + wv * 16;
    const int r = lane & 15;
    const int kg = lane >> 4;                // 0..3
    const int arow = min(n0 + r, M - 1);
    const short* aptr = hb + (size_t)arow * 2048 + by * IN_FEATS + kg * 8;
    const short* bptr = Wt + ((size_t)by * 64 + r) * IN_FEATS + kg * 8;
    f32x4 acc[4];
#pragma unroll
    for (int c = 0; c < 4; ++c) acc[c] = (f32x4){0.f, 0.f, 0.f, 0.f};
#pragma unroll
    for (int kk = 0; kk < IN_FEATS; kk += 32) {
        bf16x8 a = *(const bf16x8*)(aptr + kk);
#pragma unroll
        for (int c = 0; c < 4; ++c) {
            bf16x8 b = *(const bf16x8*)(bptr + (size_t)c * 16 * IN_FEATS + kk);
            acc[c] = __builtin_amdgcn_mfma_f32_16x16x32_bf16(a, b, acc[c], 0, 0, 0);
        }
    }
    const int orow0 = n0 + kg * 4;
#pragma unroll
    for (int c = 0; c < 4; ++c) {
#pragma unroll
        for (int i = 0; i < 4; ++i) {
            int rr = orow0 + i;
            if (rr < M) out[(size_t)rr * HD + by * 64 + c * 16 + r] = acc[c][i];
        }
    }
}

// ---------------- launch ----------------

extern "C" void kernel_launch(void* const* d_in, const int* in_sizes, int n_in,
                              void* d_out, int out_size, void* d_ws, size_t ws_size,
                              hipStream_t stream) {
    const float* feat   = (const float*)d_in[0];
    const float* W      = (const float*)d_in[1];
    const float* attn_l = (const float*)d_in[2];
    const float* attn_r = (const float*)d_in[3];
    const float* adj    = (const float*)d_in[4];
    const int*   src    = (const int*)d_in[5];
    const int*   dst    = (const int*)d_in[6];
    const int*   idxp   = (const int*)d_in[7];
    float* out = (float*)d_out;

    const int M = in_sizes[0] / IN_FEATS;  // 10000
    const int E = in_sizes[5];             // 320000

    char* ws = (char*)d_ws;
    size_t off = 0;
    auto alloc = [&](size_t bytes) -> void* {
        off = (off + 255) & ~(size_t)255;
        void* p = ws + off;
        off += bytes;
        return p;
    };
    unsigned short* hbuf  = (unsigned short*)alloc((size_t)M * 2048 * sizeof(short));
    unsigned short* featb = (unsigned short*)alloc((size_t)M * IN_FEATS * sizeof(short));
    unsigned short* Wt    = (unsigned short*)alloc((size_t)HD * IN_FEATS * sizeof(short));
    float* wlr       = (float*)alloc((size_t)IN_FEATS * 16 * sizeof(float));
    float* el        = (float*)alloc((size_t)M * NUM_HEADS * sizeof(float));
    float* er        = (float*)alloc((size_t)M * NUM_HEADS * sizeof(float));
    int*   deg       = (int*)alloc((size_t)M * sizeof(int));
    int*   row_start = (int*)alloc((size_t)(M + 1) * sizeof(int));
    int*   cursor    = (int*)alloc((size_t)M * sizeof(int));
    int*   slot_src  = (int*)alloc((size_t)E * sizeof(int));

    hipMemsetAsync(deg, 0, (size_t)M * sizeof(int), stream);

    const int nb_cnt = (E + 255) / 256;            // 1250
    const int nb_wlr = IN_FEATS / 4;               // 64
    k1_kernel<<<nb_cnt + 32 + nb_wlr, 256, 0, stream>>>(W, attn_l, attn_r, dst, deg,
                                                        wlr, Wt, E, nb_cnt);
    scan_kernel<<<1, 1024, 0, stream>>>(deg, row_start, cursor, M);
    const int nb_elr = (M + 3) / 4;                // 2500
    k3_kernel<<<nb_cnt + nb_elr, 256, 0, stream>>>(src, dst, cursor, slot_src,
                                                   feat, wlr, el, er, featb, E, M, nb_cnt);
    agg_kernel<<<M, 256, 0, stream>>>(featb, el, er, adj, row_start, slot_src, idxp, hbuf);
    dim3 og((M + 63) / 64, NUM_HEADS);
    out_gemm_kernel<<<og, 256, 0, stream>>>((const short*)hbuf, (const short*)Wt, out, M);
}